// Round 13
// baseline (148.252 us; speedup 1.0000x reference)
//
#include <hip/hip_runtime.h>

#define DIMK 128
#define POS_PER_BLOCK 512
#define NCHUNK 8            // 8 chunks x 4 tiles x 16 pos = 512
#define NODES_PER_BLOCK 256 // 4 waves x 64 nodes

typedef __bf16 bf16x8 __attribute__((ext_vector_type(8)));
typedef float  f32x4  __attribute__((ext_vector_type(4)));

// ---- helpers ---------------------------------------------------------------
__device__ inline unsigned short f32_to_bf16_rne(float f) {
    unsigned u = __float_as_uint(f);
    u += 0x7FFFu + ((u >> 16) & 1u);      // round-to-nearest-even
    return (unsigned short)(u >> 16);
}

// Fragment-pack layout for a 16-row tile (= 2048 ushorts = 4KB):
//   ushort offset = tile*2048 + kk*512 + (kb*16 + col)*8 + j
// per-lane (lane = kb*16+col) a fragment load is base + kk*512 + lane*8.
// The same packing serves either MFMA operand (verified r1-r12 both ways).

// ---- kernel 1: pack fp32 rows -> scaled bf16 fragment tiles + row norms ----
__global__ void pack_rows(const float* __restrict__ src,
                          unsigned short* __restrict__ dst,
                          float* __restrict__ norm2,
                          int n_valid, int n_rows_pad, float scale) {
    int wave = threadIdx.x >> 6, lane = threadIdx.x & 63;
    int row = blockIdx.x * 4 + wave;
    if (row >= n_rows_pad) return;
    int srow = min(row, n_valid - 1);
    int e = lane * 2;
    float2 v = *(const float2*)(src + (size_t)srow * DIMK + e);
    unsigned pk = (unsigned)f32_to_bf16_rne(scale * v.x) |
                  ((unsigned)f32_to_bf16_rne(scale * v.y) << 16);
    int tile = row >> 4, col = row & 15;
    int kk = e >> 5, kb = (e >> 3) & 3, j = e & 7;
    size_t off = (size_t)tile * 2048 + kk * 512 + (kb * 16 + col) * 8 + j;
    *(unsigned*)(dst + off) = pk;           // j even -> dword aligned
    float s = v.x * v.x + v.y * v.y;        // norms from UNscaled values
#pragma unroll
    for (int o = 1; o < 64; o <<= 1) s += __shfl_xor(s, o, 64);
    if (lane == 0) norm2[row] = s;
}

// ---- kernel 2: segment counts -> per-position weight array (SoA) -----------
__global__ void seg_weights(const int* __restrict__ ids,
                            const int* __restrict__ nseg_p,
                            float* __restrict__ wsa, int n_pos) {
    __shared__ int   cnt[256];
    __shared__ float w[256];
    int nseg = nseg_p[0];
    if (nseg > 256) nseg = 256;
    int t = threadIdx.x;
    if (t < nseg) cnt[t] = 0;
    __syncthreads();
    for (int p = t; p < n_pos; p += blockDim.x) atomicAdd(&cnt[ids[p]], 1);
    __syncthreads();
    if (t < nseg) w[t] = 1.0f / ((float)nseg * (float)max(cnt[t], 1));
    __syncthreads();
    for (int p = t; p < n_pos; p += blockDim.x) wsa[p] = w[ids[p]];
}

// ---- kernel 3: fused cross-GEMM + sqrt + weighted reduce -------------------
// OPERAND-SWAPPED: A = pred fragments (4 groups x 16 nodes, registers),
// B = staged target tile. C[row=node, col=position] -> t2/w are per-col
// scalars (b32), p2 per-row constants; acc is per-node, reduced over the 16
// col-lanes at the end. 4 waves x 64 nodes = 256 nodes/block, 512 pos/block,
// r12 staging skeleton: 2x16KB chunk double-buffer, counted vmcnt(4).
__global__ __launch_bounds__(256, 4)
void l2dist_main(const unsigned short* __restrict__ pb,   // packed bf16 pred
                 const float* __restrict__ p2,
                 const unsigned short* __restrict__ tb,   // packed bf16(-2*t)
                 const float* __restrict__ t2g,
                 const float* __restrict__ wg,
                 float* __restrict__ out,
                 int n_nodes) {
    __shared__ __align__(16) unsigned short lbuf[2][8192];   // 2 x 16KB chunks
    __shared__ __align__(16) float t2_lds[POS_PER_BLOCK];
    __shared__ __align__(16) float w_lds[POS_PER_BLOCK];

    const int tid  = threadIdx.x;
    const int lane = tid & 63;
    const int wave = tid >> 6;
    const int col  = lane & 15;
    const int kb   = lane >> 4;
    const int n0   = blockIdx.y * NODES_PER_BLOCK + wave * 64;
    const int tbase = blockIdx.x * (POS_PER_BLOCK / 16);
    const int rbase = blockIdx.x * POS_PER_BLOCK;

    // ---- A side: pred fragments for 4 node groups + per-row norms ----
    bf16x8 pfrag[4][4];          // [group][kk] — all indices literal below
    f32x4  p2r[4];               // p2 for rows kb*4+{0..3} of each group
    const unsigned short* bp = pb + ((size_t)(n0 >> 4)) * 2048 + (size_t)lane * 8;
#pragma unroll
    for (int g = 0; g < 4; ++g) {
#pragma unroll
        for (int kk = 0; kk < 4; ++kk)
            pfrag[g][kk] = *(const bf16x8*)(bp + g * 2048 + kk * 512);
        p2r[g] = *(const f32x4*)(p2 + n0 + g * 16 + kb * 4);
    }

    // ---- t2 / w -> LDS (plain loads + ds_write; before stage issue) ----
    t2_lds[tid]       = t2g[rbase + tid];
    t2_lds[tid + 256] = t2g[rbase + tid + 256];
    w_lds[tid]        = wg[rbase + tid];
    w_lds[tid + 256]  = wg[rbase + tid + 256];

    // ---- chunk staging (all loop VMEM is global_load_lds) ----
    const unsigned short* sgp = tb + (size_t)tbase * 2048 + wave * 512 + lane * 8;
#define STAGE(C)                                                               \
    _Pragma("unroll")                                                          \
    for (int t_ = 0; t_ < 4; ++t_) {                                           \
        __builtin_amdgcn_global_load_lds(                                      \
            (const __attribute__((address_space(1))) unsigned int*)(const void*)\
                (sgp + (size_t)((C) * 4 + t_) * 2048),                         \
            (__attribute__((address_space(3))) unsigned int*)(void*)           \
                (&lbuf[(C) & 1][t_ * 2048] + wave * 512),                      \
            16, 0, 0);                                                         \
    }

    STAGE(0);
    STAGE(1);

    // publish t2/w LDS writes (stage loads NOT drained)
    asm volatile("s_waitcnt lgkmcnt(0)" ::: "memory");
    __builtin_amdgcn_s_barrier();

    f32x4 acc0 = {0.f,0.f,0.f,0.f}, acc1 = {0.f,0.f,0.f,0.f};
    f32x4 acc2 = {0.f,0.f,0.f,0.f}, acc3 = {0.f,0.f,0.f,0.f};

#pragma unroll
    for (int c = 0; c < NCHUNK; ++c) {
        if (c < NCHUNK - 1) { asm volatile("s_waitcnt vmcnt(4)" ::: "memory"); }
        else                { asm volatile("s_waitcnt vmcnt(0)" ::: "memory"); }
        __builtin_amdgcn_s_barrier();       // every wave's quarter landed

        __builtin_amdgcn_s_setprio(1);
#pragma unroll
        for (int t = 0; t < 4; ++t) {
            const unsigned short* rb = &lbuf[c & 1][t * 2048] + lane * 8;
            bf16x8 a0 = *(const bf16x8*)(rb);
            bf16x8 a1 = *(const bf16x8*)(rb + 512);
            bf16x8 a2 = *(const bf16x8*)(rb + 1024);
            bf16x8 a3 = *(const bf16x8*)(rb + 1536);

            int pr = (c * 4 + t) * 16 + col;
            float t2c = t2_lds[pr];
            float wc  = w_lds[pr];

            // groups 0,1 (two interleaved chains)
            f32x4 d0 = p2r[0] + t2c;        // C-init = p2 + t2
            f32x4 d1 = p2r[1] + t2c;
            d0 = __builtin_amdgcn_mfma_f32_16x16x32_bf16(pfrag[0][0], a0, d0, 0, 0, 0);
            d1 = __builtin_amdgcn_mfma_f32_16x16x32_bf16(pfrag[1][0], a0, d1, 0, 0, 0);
            d0 = __builtin_amdgcn_mfma_f32_16x16x32_bf16(pfrag[0][1], a1, d0, 0, 0, 0);
            d1 = __builtin_amdgcn_mfma_f32_16x16x32_bf16(pfrag[1][1], a1, d1, 0, 0, 0);
            d0 = __builtin_amdgcn_mfma_f32_16x16x32_bf16(pfrag[0][2], a2, d0, 0, 0, 0);
            d1 = __builtin_amdgcn_mfma_f32_16x16x32_bf16(pfrag[1][2], a2, d1, 0, 0, 0);
            d0 = __builtin_amdgcn_mfma_f32_16x16x32_bf16(pfrag[0][3], a3, d0, 0, 0, 0);
            d1 = __builtin_amdgcn_mfma_f32_16x16x32_bf16(pfrag[1][3], a3, d1, 0, 0, 0);

            // groups 2,3
            f32x4 e0 = p2r[2] + t2c;
            f32x4 e1 = p2r[3] + t2c;
            e0 = __builtin_amdgcn_mfma_f32_16x16x32_bf16(pfrag[2][0], a0, e0, 0, 0, 0);
            e1 = __builtin_amdgcn_mfma_f32_16x16x32_bf16(pfrag[3][0], a0, e1, 0, 0, 0);
            e0 = __builtin_amdgcn_mfma_f32_16x16x32_bf16(pfrag[2][1], a1, e0, 0, 0, 0);
            e1 = __builtin_amdgcn_mfma_f32_16x16x32_bf16(pfrag[3][1], a1, e1, 0, 0, 0);
            e0 = __builtin_amdgcn_mfma_f32_16x16x32_bf16(pfrag[2][2], a2, e0, 0, 0, 0);
            e1 = __builtin_amdgcn_mfma_f32_16x16x32_bf16(pfrag[3][2], a2, e1, 0, 0, 0);
            e0 = __builtin_amdgcn_mfma_f32_16x16x32_bf16(pfrag[2][3], a3, e0, 0, 0, 0);
            e1 = __builtin_amdgcn_mfma_f32_16x16x32_bf16(pfrag[3][3], a3, e1, 0, 0, 0);

#pragma unroll
            for (int j = 0; j < 4; ++j) {
                acc0[j] = fmaf(wc, __builtin_amdgcn_sqrtf(fmaxf(d0[j], 0.f)), acc0[j]);
                acc1[j] = fmaf(wc, __builtin_amdgcn_sqrtf(fmaxf(d1[j], 0.f)), acc1[j]);
                acc2[j] = fmaf(wc, __builtin_amdgcn_sqrtf(fmaxf(e0[j], 0.f)), acc2[j]);
                acc3[j] = fmaf(wc, __builtin_amdgcn_sqrtf(fmaxf(e1[j], 0.f)), acc3[j]);
            }
        }
        __builtin_amdgcn_s_setprio(0);

        if (c + 2 < NCHUNK) {
            __builtin_amdgcn_s_barrier();   // all waves done reading buf[c&1]
            STAGE(c + 2);                   // refill with chunk c+2
        }
    }
#undef STAGE

    // reduce over the 16 column-lanes (lane bits 0..3) -> per-node totals
#pragma unroll
    for (int m = 1; m <= 8; m <<= 1) {
#pragma unroll
        for (int j = 0; j < 4; ++j) {
            acc0[j] += __shfl_xor(acc0[j], m, 64);
            acc1[j] += __shfl_xor(acc1[j], m, 64);
            acc2[j] += __shfl_xor(acc2[j], m, 64);
            acc3[j] += __shfl_xor(acc3[j], m, 64);
        }
    }
    if (col == 0) {
        int nb = n0 + kb * 4;               // rows kb*4+{0..3} of each group
#pragma unroll
        for (int j = 0; j < 4; ++j) {
            if (nb + j      < n_nodes) atomicAdd(out + nb + j,      acc0[j]);
            if (nb + 16 + j < n_nodes) atomicAdd(out + nb + 16 + j, acc1[j]);
            if (nb + 32 + j < n_nodes) atomicAdd(out + nb + 32 + j, acc2[j]);
            if (nb + 48 + j < n_nodes) atomicAdd(out + nb + 48 + j, acc3[j]);
        }
    }
}

// ---- launcher --------------------------------------------------------------
extern "C" void kernel_launch(void* const* d_in, const int* in_sizes, int n_in,
                              void* d_out, int out_size, void* d_ws, size_t ws_size,
                              hipStream_t stream) {
    const float* pred  = (const float*)d_in[0];
    const float* tgt   = (const float*)d_in[1];
    const int*   ids   = (const int*)d_in[2];
    const int*   nsegp = (const int*)d_in[3];
    float* out = (float*)d_out;

    int n_nodes = in_sizes[0] / DIMK;
    int n_pos   = in_sizes[2];

    int gy = (n_nodes + NODES_PER_BLOCK - 1) / NODES_PER_BLOCK;
    int n_rows_pad = gy * NODES_PER_BLOCK;

    char* ws = (char*)d_ws;
    size_t off_pb = 0;                                        // packed pred bf16
    size_t off_tb = off_pb + (size_t)n_rows_pad * DIMK * 2;   // packed -2*target
    size_t off_p2 = off_tb + (size_t)n_pos * DIMK * 2;        // pred norms
    size_t off_t2 = off_p2 + (size_t)n_rows_pad * 4;          // target norms
    size_t off_w  = off_t2 + (size_t)n_pos * 4;               // weights
    unsigned short* pb  = (unsigned short*)(ws + off_pb);
    unsigned short* tb  = (unsigned short*)(ws + off_tb);
    float*          p2  = (float*)(ws + off_p2);
    float*          t2  = (float*)(ws + off_t2);
    float*          wsa = (float*)(ws + off_w);

    pack_rows<<<(n_rows_pad + 3) / 4, 256, 0, stream>>>(pred, pb, p2, n_nodes, n_rows_pad, 1.0f);
    pack_rows<<<(n_pos + 3) / 4, 256, 0, stream>>>(tgt, tb, t2, n_pos, n_pos, -2.0f);
    seg_weights<<<1, 1024, 0, stream>>>(ids, nsegp, wsa, n_pos);
    hipMemsetAsync(out, 0, (size_t)out_size * sizeof(float), stream);

    dim3 grid(n_pos / POS_PER_BLOCK, gy);    // (4, 196) position-fast
    l2dist_main<<<grid, 256, 0, stream>>>(pb, p2, tb, t2, wsa, out, n_nodes);
}

// Round 14
// 61.353 us; speedup vs baseline: 2.4164x; 2.4164x over previous
//
#include <hip/hip_runtime.h>

#define DIMK 128
#define POS_PER_BLOCK 512
#define NCHUNK 8            // 8 chunks x 4 tiles x 16 pos = 512
#define NODES_PER_BLOCK 256 // 4 waves x 64 nodes

typedef __bf16 bf16x8 __attribute__((ext_vector_type(8)));
typedef float  f32x4  __attribute__((ext_vector_type(4)));

// ---- helpers ---------------------------------------------------------------
__device__ inline unsigned short f32_to_bf16_rne(float f) {
    unsigned u = __float_as_uint(f);
    u += 0x7FFFu + ((u >> 16) & 1u);      // round-to-nearest-even
    return (unsigned short)(u >> 16);
}

// Fragment-pack layout for a 16-row tile (= 2048 ushorts = 4KB):
//   ushort offset = tile*2048 + kk*512 + (kb*16 + col)*8 + j
// per-lane (lane = kb*16+col) a fragment load is base + kk*512 + lane*8.

// ---- kernel 1: pack fp32 rows -> scaled bf16 fragment tiles + row norms ----
__global__ void pack_rows(const float* __restrict__ src,
                          unsigned short* __restrict__ dst,
                          float* __restrict__ norm2,
                          int n_valid, int n_rows_pad, float scale) {
    int wave = threadIdx.x >> 6, lane = threadIdx.x & 63;
    int row = blockIdx.x * 4 + wave;
    if (row >= n_rows_pad) return;
    int srow = min(row, n_valid - 1);
    int e = lane * 2;
    float2 v = *(const float2*)(src + (size_t)srow * DIMK + e);
    unsigned pk = (unsigned)f32_to_bf16_rne(scale * v.x) |
                  ((unsigned)f32_to_bf16_rne(scale * v.y) << 16);
    int tile = row >> 4, col = row & 15;
    int kk = e >> 5, kb = (e >> 3) & 3, j = e & 7;
    size_t off = (size_t)tile * 2048 + kk * 512 + (kb * 16 + col) * 8 + j;
    *(unsigned*)(dst + off) = pk;           // j even -> dword aligned
    float s = v.x * v.x + v.y * v.y;        // norms from UNscaled values
#pragma unroll
    for (int o = 1; o < 64; o <<= 1) s += __shfl_xor(s, o, 64);
    if (lane == 0) norm2[row] = s;
}

// ---- kernel 2: segment counts -> per-position weight array (SoA) -----------
__global__ void seg_weights(const int* __restrict__ ids,
                            const int* __restrict__ nseg_p,
                            float* __restrict__ wsa, int n_pos) {
    __shared__ int   cnt[256];
    __shared__ float w[256];
    int nseg = nseg_p[0];
    if (nseg > 256) nseg = 256;
    int t = threadIdx.x;
    if (t < nseg) cnt[t] = 0;
    __syncthreads();
    for (int p = t; p < n_pos; p += blockDim.x) atomicAdd(&cnt[ids[p]], 1);
    __syncthreads();
    if (t < nseg) w[t] = 1.0f / ((float)nseg * (float)max(cnt[t], 1));
    __syncthreads();
    for (int p = t; p < n_pos; p += blockDim.x) wsa[p] = w[ids[p]];
}

// ---- kernel 3: fused cross-GEMM + sqrt + weighted reduce -------------------
// OPERAND-SWAPPED: A = pred fragments (4 groups x 16 nodes, registers),
// B = staged target tile. C[row=node, col=position] -> t2/w are per-col
// scalars (b32), p2 per-row constants. launch_bounds(256,3): VGPR cap ~170,
// fits the ~150-reg working set WITHOUT spill (r13 spilled at the 128 cap).
__global__ __launch_bounds__(256, 3)
void l2dist_main(const unsigned short* __restrict__ pb,   // packed bf16 pred
                 const float* __restrict__ p2,
                 const unsigned short* __restrict__ tb,   // packed bf16(-2*t)
                 const float* __restrict__ t2g,
                 const float* __restrict__ wg,
                 float* __restrict__ out,
                 int n_nodes) {
    __shared__ __align__(16) unsigned short lbuf[2][8192];   // 2 x 16KB chunks
    __shared__ __align__(16) float t2_lds[POS_PER_BLOCK];
    __shared__ __align__(16) float w_lds[POS_PER_BLOCK];

    const int tid  = threadIdx.x;
    const int lane = tid & 63;
    const int wave = tid >> 6;
    const int col  = lane & 15;
    const int kb   = lane >> 4;
    const int n0   = blockIdx.y * NODES_PER_BLOCK + wave * 64;
    const int tbase = blockIdx.x * (POS_PER_BLOCK / 16);
    const int rbase = blockIdx.x * POS_PER_BLOCK;

    // ---- A side: pred fragments for 4 node groups + per-row norms ----
    bf16x8 pfrag[4][4];          // [group][kk] — all indices literal below
    f32x4  p2r[4];               // p2 for rows kb*4+{0..3} of each group
    const unsigned short* bp = pb + ((size_t)(n0 >> 4)) * 2048 + (size_t)lane * 8;
#pragma unroll
    for (int g = 0; g < 4; ++g) {
#pragma unroll
        for (int kk = 0; kk < 4; ++kk)
            pfrag[g][kk] = *(const bf16x8*)(bp + g * 2048 + kk * 512);
        p2r[g] = *(const f32x4*)(p2 + n0 + g * 16 + kb * 4);
    }

    // ---- t2 / w -> LDS (plain loads + ds_write; before stage issue) ----
    t2_lds[tid]       = t2g[rbase + tid];
    t2_lds[tid + 256] = t2g[rbase + tid + 256];
    w_lds[tid]        = wg[rbase + tid];
    w_lds[tid + 256]  = wg[rbase + tid + 256];

    // ---- chunk staging (all loop VMEM is global_load_lds) ----
    const unsigned short* sgp = tb + (size_t)tbase * 2048 + wave * 512 + lane * 8;
#define STAGE(C)                                                               \
    _Pragma("unroll")                                                          \
    for (int t_ = 0; t_ < 4; ++t_) {                                           \
        __builtin_amdgcn_global_load_lds(                                      \
            (const __attribute__((address_space(1))) unsigned int*)(const void*)\
                (sgp + (size_t)((C) * 4 + t_) * 2048),                         \
            (__attribute__((address_space(3))) unsigned int*)(void*)           \
                (&lbuf[(C) & 1][t_ * 2048] + wave * 512),                      \
            16, 0, 0);                                                         \
    }

    STAGE(0);
    STAGE(1);

    // publish t2/w LDS writes (stage loads NOT drained)
    asm volatile("s_waitcnt lgkmcnt(0)" ::: "memory");
    __builtin_amdgcn_s_barrier();

    f32x4 acc0 = {0.f,0.f,0.f,0.f}, acc1 = {0.f,0.f,0.f,0.f};
    f32x4 acc2 = {0.f,0.f,0.f,0.f}, acc3 = {0.f,0.f,0.f,0.f};

#pragma unroll
    for (int c = 0; c < NCHUNK; ++c) {
        if (c < NCHUNK - 1) { asm volatile("s_waitcnt vmcnt(4)" ::: "memory"); }
        else                { asm volatile("s_waitcnt vmcnt(0)" ::: "memory"); }
        __builtin_amdgcn_s_barrier();       // every wave's quarter landed

        __builtin_amdgcn_s_setprio(1);
#pragma unroll
        for (int t = 0; t < 4; ++t) {
            const unsigned short* rb = &lbuf[c & 1][t * 2048] + lane * 8;
            bf16x8 a0 = *(const bf16x8*)(rb);
            bf16x8 a1 = *(const bf16x8*)(rb + 512);
            bf16x8 a2 = *(const bf16x8*)(rb + 1024);
            bf16x8 a3 = *(const bf16x8*)(rb + 1536);

            int pr = (c * 4 + t) * 16 + col;
            float t2c = t2_lds[pr];
            float wc  = w_lds[pr];

            // groups 0,1 (two interleaved chains)
            f32x4 d0 = p2r[0] + t2c;        // C-init = p2 + t2
            f32x4 d1 = p2r[1] + t2c;
            d0 = __builtin_amdgcn_mfma_f32_16x16x32_bf16(pfrag[0][0], a0, d0, 0, 0, 0);
            d1 = __builtin_amdgcn_mfma_f32_16x16x32_bf16(pfrag[1][0], a0, d1, 0, 0, 0);
            d0 = __builtin_amdgcn_mfma_f32_16x16x32_bf16(pfrag[0][1], a1, d0, 0, 0, 0);
            d1 = __builtin_amdgcn_mfma_f32_16x16x32_bf16(pfrag[1][1], a1, d1, 0, 0, 0);
            d0 = __builtin_amdgcn_mfma_f32_16x16x32_bf16(pfrag[0][2], a2, d0, 0, 0, 0);
            d1 = __builtin_amdgcn_mfma_f32_16x16x32_bf16(pfrag[1][2], a2, d1, 0, 0, 0);
            d0 = __builtin_amdgcn_mfma_f32_16x16x32_bf16(pfrag[0][3], a3, d0, 0, 0, 0);
            d1 = __builtin_amdgcn_mfma_f32_16x16x32_bf16(pfrag[1][3], a3, d1, 0, 0, 0);

#pragma unroll
            for (int j = 0; j < 4; ++j) {
                acc0[j] = fmaf(wc, __builtin_amdgcn_sqrtf(fmaxf(d0[j], 0.f)), acc0[j]);
                acc1[j] = fmaf(wc, __builtin_amdgcn_sqrtf(fmaxf(d1[j], 0.f)), acc1[j]);
            }

            // groups 2,3 (reuse d0/d1 registers)
            d0 = p2r[2] + t2c;
            d1 = p2r[3] + t2c;
            d0 = __builtin_amdgcn_mfma_f32_16x16x32_bf16(pfrag[2][0], a0, d0, 0, 0, 0);
            d1 = __builtin_amdgcn_mfma_f32_16x16x32_bf16(pfrag[3][0], a0, d1, 0, 0, 0);
            d0 = __builtin_amdgcn_mfma_f32_16x16x32_bf16(pfrag[2][1], a1, d0, 0, 0, 0);
            d1 = __builtin_amdgcn_mfma_f32_16x16x32_bf16(pfrag[3][1], a1, d1, 0, 0, 0);
            d0 = __builtin_amdgcn_mfma_f32_16x16x32_bf16(pfrag[2][2], a2, d0, 0, 0, 0);
            d1 = __builtin_amdgcn_mfma_f32_16x16x32_bf16(pfrag[3][2], a2, d1, 0, 0, 0);
            d0 = __builtin_amdgcn_mfma_f32_16x16x32_bf16(pfrag[2][3], a3, d0, 0, 0, 0);
            d1 = __builtin_amdgcn_mfma_f32_16x16x32_bf16(pfrag[3][3], a3, d1, 0, 0, 0);

#pragma unroll
            for (int j = 0; j < 4; ++j) {
                acc2[j] = fmaf(wc, __builtin_amdgcn_sqrtf(fmaxf(d0[j], 0.f)), acc2[j]);
                acc3[j] = fmaf(wc, __builtin_amdgcn_sqrtf(fmaxf(d1[j], 0.f)), acc3[j]);
            }
        }
        __builtin_amdgcn_s_setprio(0);

        if (c + 2 < NCHUNK) {
            __builtin_amdgcn_s_barrier();   // all waves done reading buf[c&1]
            STAGE(c + 2);                   // refill with chunk c+2
        }
    }
#undef STAGE

    // reduce over the 16 column-lanes (lane bits 0..3) -> per-node totals
#pragma unroll
    for (int m = 1; m <= 8; m <<= 1) {
#pragma unroll
        for (int j = 0; j < 4; ++j) {
            acc0[j] += __shfl_xor(acc0[j], m, 64);
            acc1[j] += __shfl_xor(acc1[j], m, 64);
            acc2[j] += __shfl_xor(acc2[j], m, 64);
            acc3[j] += __shfl_xor(acc3[j], m, 64);
        }
    }
    if (col == 0) {
        int nb = n0 + kb * 4;               // rows kb*4+{0..3} of each group
#pragma unroll
        for (int j = 0; j < 4; ++j) {
            if (nb + j      < n_nodes) atomicAdd(out + nb + j,      acc0[j]);
            if (nb + 16 + j < n_nodes) atomicAdd(out + nb + 16 + j, acc1[j]);
            if (nb + 32 + j < n_nodes) atomicAdd(out + nb + 32 + j, acc2[j]);
            if (nb + 48 + j < n_nodes) atomicAdd(out + nb + 48 + j, acc3[j]);
        }
    }
}

// ---- launcher --------------------------------------------------------------
extern "C" void kernel_launch(void* const* d_in, const int* in_sizes, int n_in,
                              void* d_out, int out_size, void* d_ws, size_t ws_size,
                              hipStream_t stream) {
    const float* pred  = (const float*)d_in[0];
    const float* tgt   = (const float*)d_in[1];
    const int*   ids   = (const int*)d_in[2];
    const int*   nsegp = (const int*)d_in[3];
    float* out = (float*)d_out;

    int n_nodes = in_sizes[0] / DIMK;
    int n_pos   = in_sizes[2];

    int gy = (n_nodes + NODES_PER_BLOCK - 1) / NODES_PER_BLOCK;
    int n_rows_pad = gy * NODES_PER_BLOCK;

    char* ws = (char*)d_ws;
    size_t off_pb = 0;                                        // packed pred bf16
    size_t off_tb = off_pb + (size_t)n_rows_pad * DIMK * 2;   // packed -2*target
    size_t off_p2 = off_tb + (size_t)n_pos * DIMK * 2;        // pred norms
    size_t off_t2 = off_p2 + (size_t)n_rows_pad * 4;          // target norms
    size_t off_w  = off_t2 + (size_t)n_pos * 4;               // weights
    unsigned short* pb  = (unsigned short*)(ws + off_pb);
    unsigned short* tb  = (unsigned short*)(ws + off_tb);
    float*          p2  = (float*)(ws + off_p2);
    float*          t2  = (float*)(ws + off_t2);
    float*          wsa = (float*)(ws + off_w);

    pack_rows<<<(n_rows_pad + 3) / 4, 256, 0, stream>>>(pred, pb, p2, n_nodes, n_rows_pad, 1.0f);
    pack_rows<<<(n_pos + 3) / 4, 256, 0, stream>>>(tgt, tb, t2, n_pos, n_pos, -2.0f);
    seg_weights<<<1, 1024, 0, stream>>>(ids, nsegp, wsa, n_pos);
    hipMemsetAsync(out, 0, (size_t)out_size * sizeof(float), stream);

    dim3 grid(n_pos / POS_PER_BLOCK, gy);    // (4, 196) position-fast
    l2dist_main<<<grid, 256, 0, stream>>>(pb, p2, tb, t2, wsa, out, n_nodes);
}

// Round 15
// 56.069 us; speedup vs baseline: 2.6441x; 1.0942x over previous
//
#include <hip/hip_runtime.h>

#define DIMK 128
#define SLICE_TILES 8
#define NODES_PER_BLOCK 128

typedef __bf16 bf16x8 __attribute__((ext_vector_type(8)));
typedef float  f32x4  __attribute__((ext_vector_type(4)));

// ---- helpers ---------------------------------------------------------------
__device__ inline unsigned short f32_to_bf16_rne(float f) {
    unsigned u = __float_as_uint(f);
    u += 0x7FFFu + ((u >> 16) & 1u);      // round-to-nearest-even
    return (unsigned short)(u >> 16);
}

// Fragment-pack layout for a 16-row tile (= 2048 ushorts = 4KB):
//   ushort offset = tile*2048 + kk*512 + (kb*16 + col)*8 + j
// per-lane (lane = kb*16+col) a fragment load is base + kk*512 + lane*8.

// ---- kernel 1: pack fp32 rows -> scaled bf16 fragment tiles + row norms ----
__global__ void pack_rows(const float* __restrict__ src,
                          unsigned short* __restrict__ dst,
                          float* __restrict__ norm2,
                          int n_valid, int n_rows_pad, float scale) {
    int wave = threadIdx.x >> 6, lane = threadIdx.x & 63;
    int row = blockIdx.x * 4 + wave;
    if (row >= n_rows_pad) return;
    int srow = min(row, n_valid - 1);
    int e = lane * 2;
    float2 v = *(const float2*)(src + (size_t)srow * DIMK + e);
    unsigned pk = (unsigned)f32_to_bf16_rne(scale * v.x) |
                  ((unsigned)f32_to_bf16_rne(scale * v.y) << 16);
    int tile = row >> 4, col = row & 15;
    int kk = e >> 5, kb = (e >> 3) & 3, j = e & 7;
    size_t off = (size_t)tile * 2048 + kk * 512 + (kb * 16 + col) * 8 + j;
    *(unsigned*)(dst + off) = pk;           // j even -> dword aligned
    float s = v.x * v.x + v.y * v.y;        // norms from UNscaled values
#pragma unroll
    for (int o = 1; o < 64; o <<= 1) s += __shfl_xor(s, o, 64);
    if (lane == 0) norm2[row] = s;
}

// ---- kernel 2: segment counts -> per-position weight array (SoA) -----------
__global__ void seg_weights(const int* __restrict__ ids,
                            const int* __restrict__ nseg_p,
                            float* __restrict__ wsa, int n_pos) {
    __shared__ int   cnt[256];
    __shared__ float w[256];
    int nseg = nseg_p[0];
    if (nseg > 256) nseg = 256;
    int t = threadIdx.x;
    if (t < nseg) cnt[t] = 0;
    __syncthreads();
    for (int p = t; p < n_pos; p += blockDim.x) atomicAdd(&cnt[ids[p]], 1);
    __syncthreads();
    if (t < nseg) w[t] = 1.0f / ((float)nseg * (float)max(cnt[t], 1));
    __syncthreads();
    for (int p = t; p < n_pos; p += blockDim.x) wsa[p] = w[ids[p]];
}

// ---- kernel 3: fused cross-GEMM + sqrt + weighted reduce -------------------
// r7 base (whole-slice prestage, ONE sync, barrier-free read-only compute)
// with two de-serialization changes:
//  (1) per-wave ROTATED tile order (te = (t + 2*wave) & 7) -> co-resident
//      waves sit in different phases (MFMA vs epilogue) -> cross-pipe overlap
//  (2) accumulation chain split (d*a + d*b): 4 chains of depth 2, dep
//      distance 4 issues >= MFMA latency -> no intra-chain stall.
// Target packed with scale -2 so squared distance = d + t2 + p2.
__global__ __launch_bounds__(256, 4)
void l2dist_main(const unsigned short* __restrict__ pb,   // packed bf16 pred
                 const float* __restrict__ p2,
                 const unsigned short* __restrict__ tb,   // packed bf16(-2*t)
                 const float* __restrict__ t2g,
                 const float* __restrict__ wg,
                 float* __restrict__ out,
                 int n_nodes) {
    __shared__ __align__(16) unsigned short lbuf[SLICE_TILES][2048];  // 32 KB
    __shared__ __align__(16) float t2_lds[SLICE_TILES * 16];
    __shared__ __align__(16) float w_lds[SLICE_TILES * 16];

    const int tid  = threadIdx.x;
    const int lane = tid & 63;
    const int wave = tid >> 6;
    const int col  = lane & 15;
    const int kb   = lane >> 4;
    const int n0   = blockIdx.y * NODES_PER_BLOCK + wave * 32;

    // ---- stage the whole 8-tile slice first (longest latency) ----
    const int pbase = blockIdx.x * SLICE_TILES;
    const unsigned short* sgp = tb + (size_t)pbase * 2048 + wave * 512 + lane * 8;
    unsigned short* ldst = &lbuf[0][0] + wave * 512;
#pragma unroll
    for (int t = 0; t < SLICE_TILES; ++t) {
        __builtin_amdgcn_global_load_lds(
            (const __attribute__((address_space(1))) unsigned int*)(const void*)
                (sgp + (size_t)t * 2048),
            (__attribute__((address_space(3))) unsigned int*)(void*)
                (ldst + t * 2048),
            16, 0, 0);
    }

    // ---- t2 / w -> LDS (overlaps the stage) ----
    if (tid < SLICE_TILES * 16) {
        t2_lds[tid] = t2g[pbase * 16 + tid];
        w_lds[tid]  = wg[pbase * 16 + tid];
    }

    // ---- B fragments (2 node groups) + norms (overlaps the stage) ----
    bf16x8 bfrag[2][4];
    float p2g[2];
    const unsigned short* bp = pb + ((size_t)(n0 >> 4)) * 2048 + (size_t)lane * 8;
#pragma unroll
    for (int g = 0; g < 2; ++g) {
#pragma unroll
        for (int kk = 0; kk < 4; ++kk)
            bfrag[g][kk] = *(const bf16x8*)(bp + g * 2048 + kk * 512);
        p2g[g] = p2[n0 + g * 16 + col];
    }

    __syncthreads();    // drains stage + LDS writes; LDS read-only afterwards

    float acc0 = 0.f, acc1 = 0.f;
#pragma unroll
    for (int t = 0; t < SLICE_TILES; ++t) {
        const int te = (t + 2 * wave) & (SLICE_TILES - 1);   // de-phased order

        const unsigned short* rb = &lbuf[te][lane * 8];
        bf16x8 a0 = *(const bf16x8*)(rb);
        bf16x8 a1 = *(const bf16x8*)(rb + 512);
        bf16x8 a2 = *(const bf16x8*)(rb + 1024);
        bf16x8 a3 = *(const bf16x8*)(rb + 1536);

        f32x4 t2v = *(const f32x4*)&t2_lds[te * 16 + kb * 4];
        f32x4 wv  = *(const f32x4*)&w_lds[te * 16 + kb * 4];

        // 4 independent chains of depth 2 (dep distance 4 issues)
        f32x4 d0a = t2v + p2g[0];
        f32x4 d1a = t2v + p2g[1];
        f32x4 d0b = {0.f, 0.f, 0.f, 0.f};
        f32x4 d1b = {0.f, 0.f, 0.f, 0.f};
        d0a = __builtin_amdgcn_mfma_f32_16x16x32_bf16(a0, bfrag[0][0], d0a, 0, 0, 0);
        d1a = __builtin_amdgcn_mfma_f32_16x16x32_bf16(a0, bfrag[1][0], d1a, 0, 0, 0);
        d0b = __builtin_amdgcn_mfma_f32_16x16x32_bf16(a2, bfrag[0][2], d0b, 0, 0, 0);
        d1b = __builtin_amdgcn_mfma_f32_16x16x32_bf16(a2, bfrag[1][2], d1b, 0, 0, 0);
        d0a = __builtin_amdgcn_mfma_f32_16x16x32_bf16(a1, bfrag[0][1], d0a, 0, 0, 0);
        d1a = __builtin_amdgcn_mfma_f32_16x16x32_bf16(a1, bfrag[1][1], d1a, 0, 0, 0);
        d0b = __builtin_amdgcn_mfma_f32_16x16x32_bf16(a3, bfrag[0][3], d0b, 0, 0, 0);
        d1b = __builtin_amdgcn_mfma_f32_16x16x32_bf16(a3, bfrag[1][3], d1b, 0, 0, 0);

        f32x4 s0 = d0a + d0b;
        f32x4 s1 = d1a + d1b;
#pragma unroll
        for (int j = 0; j < 4; ++j) {
            acc0 = fmaf(wv[j], __builtin_amdgcn_sqrtf(fmaxf(s0[j], 0.f)), acc0);
            acc1 = fmaf(wv[j], __builtin_amdgcn_sqrtf(fmaxf(s1[j], 0.f)), acc1);
        }
    }

    // reduce over the 4 kb lane-groups -> per-node totals
    acc0 += __shfl_xor(acc0, 16, 64);
    acc0 += __shfl_xor(acc0, 32, 64);
    acc1 += __shfl_xor(acc1, 16, 64);
    acc1 += __shfl_xor(acc1, 32, 64);
    if (lane < 16) {
        int na = n0 + col;
        if (na      < n_nodes) atomicAdd(out + na,      acc0);
        if (na + 16 < n_nodes) atomicAdd(out + na + 16, acc1);
    }
}

// ---- launcher --------------------------------------------------------------
extern "C" void kernel_launch(void* const* d_in, const int* in_sizes, int n_in,
                              void* d_out, int out_size, void* d_ws, size_t ws_size,
                              hipStream_t stream) {
    const float* pred  = (const float*)d_in[0];
    const float* tgt   = (const float*)d_in[1];
    const int*   ids   = (const int*)d_in[2];
    const int*   nsegp = (const int*)d_in[3];
    float* out = (float*)d_out;

    int n_nodes = in_sizes[0] / DIMK;
    int n_pos   = in_sizes[2];

    int gy = (n_nodes + NODES_PER_BLOCK - 1) / NODES_PER_BLOCK;
    int n_rows_pad = gy * NODES_PER_BLOCK;

    char* ws = (char*)d_ws;
    size_t off_pb = 0;                                        // packed pred bf16
    size_t off_tb = off_pb + (size_t)n_rows_pad * DIMK * 2;   // packed -2*target
    size_t off_p2 = off_tb + (size_t)n_pos * DIMK * 2;        // pred norms
    size_t off_t2 = off_p2 + (size_t)n_rows_pad * 4;          // target norms
    size_t off_w  = off_t2 + (size_t)n_pos * 4;               // weights
    unsigned short* pb  = (unsigned short*)(ws + off_pb);
    unsigned short* tb  = (unsigned short*)(ws + off_tb);
    float*          p2  = (float*)(ws + off_p2);
    float*          t2  = (float*)(ws + off_t2);
    float*          wsa = (float*)(ws + off_w);

    pack_rows<<<(n_rows_pad + 3) / 4, 256, 0, stream>>>(pred, pb, p2, n_nodes, n_rows_pad, 1.0f);
    pack_rows<<<(n_pos + 3) / 4, 256, 0, stream>>>(tgt, tb, t2, n_pos, n_pos, -2.0f);
    seg_weights<<<1, 1024, 0, stream>>>(ids, nsegp, wsa, n_pos);
    hipMemsetAsync(out, 0, (size_t)out_size * sizeof(float), stream);

    int gx = (n_pos >> 4) / SLICE_TILES;     // 16 position slices (fast axis)
    dim3 grid(gx, gy);
    l2dist_main<<<grid, 256, 0, stream>>>(pb, p2, tb, t2, wsa, out, n_nodes);
}